// Round 4
// baseline (265.831 us; speedup 1.0000x reference)
//
#include <hip/hip_runtime.h>

// Problem constants
constexpr int Bn = 8192;   // batch
constexpr int Dd = 2048;   // dims
constexpr int Kk = 512;    // components
constexpr int Qq = 8;      // factors
constexpr int Nn = Kk * 9; // GEMM N: 8 PinvW cols + 1 g col per component = 4608
constexpr float DLOG2PI = 3763.9722f; // D * log(2*pi)

// GEMM tiling: 256x288 tile (32 comps), BK=128 fp8 bytes, 8 waves (4m x 2n).
// A operand: DIRECT FROM GLOBAL (xq is L2-resident; frag layout = linear rows).
// B operand: double-buffered LDS via global_load_lds, staged by all 8 waves.
// Per-tile LDS traffic drops 281->183 KB => below the 2495-cy MFMA floor.
constexpr int BM = 256, BN = 288, BK = 128;
constexpr int NT = Dd / BK;  // 16 K-tiles

// Quantization scales (powers of 2, folded out in the epilogue)
constexpr float SX = 16.f;   // x
constexpr float SW = 64.f;   // W columns (q<8)
constexpr float SG = 16.f;   // g column  (q==8)
constexpr float INV_UW = 1.f / (16.f * 64.f);  // u = cp/1024
constexpr float INV_UG = 1.f / (16.f * 16.f);  // s = cp/256

// Workspace layout (bytes)
constexpr size_t OFF_PSI   = 0;          // psi_inv: D*4
constexpr size_t OFF_LDP   = 8192;       // logdetPsi scalar
constexpr size_t OFF_LOGPI = 8448;       // K*4
constexpr size_t OFF_OFFK  = 10752;      // K*4
constexpr size_t OFF_MINV  = 13056;      // K*64*4
constexpr size_t OFF_XPX   = 144384;     // B*4
constexpr size_t OFF_XBF   = 177408;     // x fp8: B*D*1
constexpr size_t OFF_GT    = 33731840;   // G fp8: N*D*1  (Gq[n][d], k-contig rows)
constexpr size_t OFF_LL    = 52606208;   // B*K*4
constexpr size_t OFF_PART  = 69383424;   // 2048*4

// LDS layout for gemm_ll (bytes) — A no longer staged
constexpr int LDS_BS   = 0;        // 2 x 288*128 = 73728
constexpr int LDS_MINV = 73728;    // 32*65*4 = 8320 -> 82048
constexpr int LDS_OFFC = 82048;    // 32*4 (pad to 128) -> 82176
constexpr int LDS_CS   = 82176;    // 8 waves x 16*148*4 = 75776
constexpr int LDS_TOT  = 157952;   // <= 160 KiB

typedef float f32x4 __attribute__((ext_vector_type(4)));
typedef int   i32x4v __attribute__((ext_vector_type(4)));
typedef int   i32x8v __attribute__((ext_vector_type(8)));

__device__ inline float softplusf(float x) {
  return fmaxf(x, 0.f) + log1pf(expf(-fabsf(x)));
}
__device__ inline unsigned short f2bf(float x) {
  unsigned int u = __builtin_bit_cast(unsigned int, x);
  u = (u + 0x7fffu + ((u >> 16) & 1u)) >> 16;
  return (unsigned short)u;
}
__device__ inline unsigned int pack2(float a, float b) {
  return (unsigned int)f2bf(a) | ((unsigned int)f2bf(b) << 16);
}
__device__ inline float bf2f(unsigned int u16) {
  unsigned int v = u16 << 16;
  return __builtin_bit_cast(float, v);
}
// single float -> fp8 e4m3 (OCP on gfx950), RNE
__device__ inline unsigned char f2fp8(float x) {
  int v = __builtin_amdgcn_cvt_pk_fp8_f32(x, 0.f, 0, false);
  return (unsigned char)(v & 0xff);
}
// async global->LDS, 16B per lane; LDS dest is wave-uniform base + lane*16
__device__ inline void glds16(const unsigned char* g, char* l) {
  __builtin_amdgcn_global_load_lds(
      (const __attribute__((address_space(1))) unsigned int*)g,
      (__attribute__((address_space(3))) unsigned int*)l, 16, 0, 0);
}
// load one 32B fp8 fragment (k-bytes quad*32..+31) from a 128B swizzled row
__device__ inline i32x8v ld_frag(const char* rowp, int quad, int s8) {
  i32x4v lo = *(const i32x4v*)(rowp + (((2 * quad)     ^ s8) * 16));
  i32x4v hi = *(const i32x4v*)(rowp + (((2 * quad + 1) ^ s8) * 16));
  i32x8v r;
  r[0] = lo[0]; r[1] = lo[1]; r[2] = lo[2]; r[3] = lo[3];
  r[4] = hi[0]; r[5] = hi[1]; r[6] = hi[2]; r[7] = hi[3];
  return r;
}
// load one 32B A-fragment directly from global (linear xq row)
__device__ inline i32x8v ld_ga(const char* p) {
  i32x4v lo = *(const i32x4v*)(p);
  i32x4v hi = *(const i32x4v*)(p + 16);
  i32x8v r;
  r[0] = lo[0]; r[1] = lo[1]; r[2] = lo[2]; r[3] = lo[3];
  r[4] = hi[0]; r[5] = hi[1]; r[6] = hi[2]; r[7] = hi[3];
  return r;
}

// Raw barrier (no compiler vmcnt(0) drain, unlike __syncthreads)
#define BARRIER()                                   \
  do {                                              \
    asm volatile("" ::: "memory");                  \
    __builtin_amdgcn_s_barrier();                   \
    asm volatile("" ::: "memory");                  \
  } while (0)

// ---------------- Kernel A: psi_inv, logdetPsi, log_pi (1 block) ----------------
__global__ __launch_bounds__(256) void prep_psi(
    const float* __restrict__ psi_rho, const float* __restrict__ pi_logits,
    float* __restrict__ psi_inv, float* __restrict__ logdetPsi,
    float* __restrict__ logpi) {
  __shared__ float red[256];
  int t = threadIdx.x;
  float acc = 0.f;
  for (int d = t; d < Dd; d += 256) {
    float p = softplusf(psi_rho[d]) + 1e-5f;
    psi_inv[d] = 1.f / p;
    acc += logf(p);
  }
  red[t] = acc;
  __syncthreads();
  for (int s = 128; s > 0; s >>= 1) { if (t < s) red[t] += red[t + s]; __syncthreads(); }
  if (t == 0) *logdetPsi = red[0];
  __syncthreads();
  float mx = -3.4e38f;
  for (int i = t; i < Kk; i += 256) mx = fmaxf(mx, pi_logits[i]);
  red[t] = mx;
  __syncthreads();
  for (int s = 128; s > 0; s >>= 1) { if (t < s) red[t] = fmaxf(red[t], red[t + s]); __syncthreads(); }
  mx = red[0];
  __syncthreads();
  float se = 0.f;
  for (int i = t; i < Kk; i += 256) se += expf(pi_logits[i] - mx);
  red[t] = se;
  __syncthreads();
  for (int s = 128; s > 0; s >>= 1) { if (t < s) red[t] += red[t + s]; __syncthreads(); }
  float lse = mx + logf(red[0]);
  for (int i = t; i < Kk; i += 256) logpi[i] = pi_logits[i] - lse;
}

// ---------------- Fused prep kernel ----------------
// lower-tri packed index (row i >= col j)
#define TRI(i, j) ((i) * ((i) + 1) / 2 + (j))

__global__ __launch_bounds__(256) void prep_all(
    const float* __restrict__ x, const float* __restrict__ mu,
    const float* __restrict__ dir_raw, const float* __restrict__ scale_rho,
    const float* __restrict__ psi_inv,
    float* __restrict__ offk, float* __restrict__ Minv,
    unsigned char* __restrict__ Gq, unsigned char* __restrict__ xq,
    float* __restrict__ xPx) {
  __shared__ unsigned short sDir[Dd * 8];  // bf16 pw*dir, 32 KB (k-work)
  __shared__ float sPwmd[Dd];              // f32 pw*mu (k-work; scratch for x-work)
  __shared__ float redk[4 * 53];
  __shared__ float R[53];
  __shared__ float sAl[8], sAh[8];
  __shared__ float sLt[36], sLdt[8];       // packed Cholesky L + inv diag

  int bid = blockIdx.x;
  int t = threadIdx.x, lane = t & 63, w = t >> 6;

  if (bid >= Kk) {
    // ---- x-work: row b -> fp8 (x16) + xT Psi^-1 x ----
    int b = bid - Kk;
    const float4* xr = (const float4*)(x + (size_t)b * Dd);
    const float4* pr = (const float4*)psi_inv;
    float4 v0 = xr[2 * t], v1 = xr[2 * t + 1];
    float4 p0 = pr[2 * t], p1 = pr[2 * t + 1];
    float acc = v0.x * v0.x * p0.x + v0.y * v0.y * p0.y + v0.z * v0.z * p0.z + v0.w * v0.w * p0.w
              + v1.x * v1.x * p1.x + v1.y * v1.y * p1.y + v1.z * v1.z * p1.z + v1.w * v1.w * p1.w;
    unsigned int q0 = (unsigned int)__builtin_amdgcn_cvt_pk_fp8_f32(SX * v0.x, SX * v0.y, 0, false);
    q0 = (unsigned int)__builtin_amdgcn_cvt_pk_fp8_f32(SX * v0.z, SX * v0.w, (int)q0, true);
    unsigned int q1 = (unsigned int)__builtin_amdgcn_cvt_pk_fp8_f32(SX * v1.x, SX * v1.y, 0, false);
    q1 = (unsigned int)__builtin_amdgcn_cvt_pk_fp8_f32(SX * v1.z, SX * v1.w, (int)q1, true);
    uint2 o; o.x = q0; o.y = q1;
    *(uint2*)(xq + (size_t)b * Dd + t * 8) = o;
#pragma unroll
    for (int s2 = 32; s2; s2 >>= 1) acc += __shfl_down(acc, s2, 64);
    float* r4 = sPwmd;
    if (lane == 0) r4[w] = acc;
    __syncthreads();
    if (t == 0) xPx[b] = r4[0] + r4[1] + r4[2] + r4[3];
    return;
  }

  // ---- k-work ----
  int k = bid;
  float vals[53];
#pragma unroll
  for (int i = 0; i < 53; i++) vals[i] = 0.f;
  const float4* dirp = (const float4*)(dir_raw + (size_t)k * Dd * Qq);
  for (int d = t; d < Dd; d += 256) {
    float4 da = dirp[d * 2], db = dirp[d * 2 + 1];
    float dir8[8] = {da.x, da.y, da.z, da.w, db.x, db.y, db.z, db.w};
    float pw = psi_inv[d];
    float md = mu[(size_t)k * Dd + d];
    int c = 0;
#pragma unroll
    for (int i = 0; i < 8; i++) {
      float dip = dir8[i] * pw;
#pragma unroll
      for (int j = 0; j < 8; j++) {
        if (j < i) continue;
        vals[c] += dip * dir8[j]; c++;
      }
    }
#pragma unroll
    for (int q = 0; q < 8; q++) vals[36 + q] += dir8[q] * dir8[q];
    float mp = md * pw;
#pragma unroll
    for (int q = 0; q < 8; q++) vals[44 + q] += mp * dir8[q];
    vals[52] += md * mp;
    uint4 pk;
    pk.x = pack2(pw * dir8[0], pw * dir8[1]);
    pk.y = pack2(pw * dir8[2], pw * dir8[3]);
    pk.z = pack2(pw * dir8[4], pw * dir8[5]);
    pk.w = pack2(pw * dir8[6], pw * dir8[7]);
    *(uint4*)(sDir + d * 8) = pk;
    sPwmd[d] = mp;
  }
#pragma unroll
  for (int v = 0; v < 53; v++) {
    float val = vals[v];
#pragma unroll
    for (int o = 32; o; o >>= 1) val += __shfl_down(val, o, 64);
    if (lane == 0) redk[w * 53 + v] = val;
  }
  __syncthreads();
  if (t < 53) R[t] = redk[t] + redk[53 + t] + redk[106 + t] + redk[159 + t];
  __syncthreads();
  if (t == 0) {
    float Sf[8][8];
    {
      int c2 = 0;
#pragma unroll
      for (int i = 0; i < 8; i++) {
#pragma unroll
        for (int j = 0; j < 8; j++) {
          if (j < i) continue;
          float v = R[c2++]; Sf[i][j] = v; Sf[j][i] = v;
        }
      }
    }
    float alpha[8];
#pragma unroll
    for (int q = 0; q < 8; q++) {
      float nr = fmaxf(sqrtf(R[36 + q]), 1e-5f);
      alpha[q] = softplusf(scale_rho[(size_t)k * 8 + q]) / nr;
    }
    float Mm[8][8];
#pragma unroll
    for (int i = 0; i < 8; i++)
#pragma unroll
      for (int j = 0; j < 8; j++)
        Mm[i][j] = alpha[i] * alpha[j] * Sf[i][j] + (i == j ? 1.f : 0.f);
    float L[8][8], Ld[8];
#pragma unroll
    for (int i = 0; i < 8; i++) {
#pragma unroll
      for (int j = 0; j < 8; j++) {
        if (j > i) continue;
        float s2 = Mm[i][j];
#pragma unroll
        for (int p = 0; p < 8; p++) { if (p < j) s2 -= L[i][p] * L[j][p]; }
        if (i == j) { L[i][i] = sqrtf(s2); Ld[i] = 1.f / L[i][i]; }
        else        L[i][j] = s2 * Ld[j];
      }
    }
    float logdetM = 0.f;
#pragma unroll
    for (int i = 0; i < 8; i++) logdetM += 2.f * logf(L[i][i]);
    float wv[8];
#pragma unroll
    for (int q = 0; q < 8; q++) wv[q] = alpha[q] * R[44 + q];
    float y[8], h[8];
#pragma unroll
    for (int i = 0; i < 8; i++) {
      float s2 = wv[i];
#pragma unroll
      for (int p = 0; p < 8; p++) { if (p < i) s2 -= L[i][p] * y[p]; }
      y[i] = s2 * Ld[i];
    }
#pragma unroll
    for (int i = 7; i >= 0; i--) {
      float s2 = y[i];
#pragma unroll
      for (int p = 0; p < 8; p++) { if (p > i) s2 -= L[p][i] * h[p]; }
      h[i] = s2 * Ld[i];
    }
    float cc = R[52];
#pragma unroll
    for (int q = 0; q < 8; q++) cc -= wv[q] * h[q];
    // publish L, Ld for the parallel per-column Minv solves
    {
      int c3 = 0;
#pragma unroll
      for (int i = 0; i < 8; i++)
#pragma unroll
        for (int j = 0; j < 8; j++) { if (j <= i) sLt[c3++] = L[i][j]; }
#pragma unroll
      for (int i = 0; i < 8; i++) sLdt[i] = Ld[i];
    }
    offk[k] = -0.5f * (DLOG2PI + logdetM + cc);
#pragma unroll
    for (int q = 0; q < 8; q++) { sAl[q] = alpha[q]; sAh[q] = alpha[q] * h[q]; }
  }
  __syncthreads();
  // Minv: 8 independent column solves, one per thread
  if (t < 8) {
    int col = t;
    float yy[8], z[8];
#pragma unroll
    for (int i = 0; i < 8; i++) {
      float s2 = (i == col) ? 1.f : 0.f;
#pragma unroll
      for (int p = 0; p < 8; p++) { if (p < i) s2 -= sLt[TRI(i, p)] * yy[p]; }
      yy[i] = s2 * sLdt[i];
    }
#pragma unroll
    for (int i = 7; i >= 0; i--) {
      float s2 = yy[i];
#pragma unroll
      for (int p = 0; p < 8; p++) { if (p > i) s2 -= sLt[TRI(p, i)] * z[p]; }
      z[i] = s2 * sLdt[i];
    }
#pragma unroll
    for (int r2 = 0; r2 < 8; r2++) Minv[(size_t)k * 64 + r2 * 8 + col] = z[r2];
  }
  float al[8], ah[8];
#pragma unroll
  for (int q = 0; q < 8; q++) { al[q] = sAl[q]; ah[q] = sAh[q]; }
  for (int d = t; d < Dd; d += 256) {
    uint4 pk = *(const uint4*)(sDir + d * 8);
    float pd[8];
    pd[0] = bf2f(pk.x & 0xffffu); pd[1] = bf2f(pk.x >> 16);
    pd[2] = bf2f(pk.y & 0xffffu); pd[3] = bf2f(pk.y >> 16);
    pd[4] = bf2f(pk.z & 0xffffu); pd[5] = bf2f(pk.z >> 16);
    pd[6] = bf2f(pk.w & 0xffffu); pd[7] = bf2f(pk.w >> 16);
    float gs = 0.f;
#pragma unroll
    for (int q = 0; q < 8; q++) {
      Gq[((size_t)(k * 9 + q)) * Dd + d] = f2fp8(SW * al[q] * pd[q]);
      gs += ah[q] * pd[q];
    }
    Gq[((size_t)(k * 9 + 8)) * Dd + d] = f2fp8(SG * (sPwmd[d] - gs));
  }
}

// ---------------- Kernel D: fused MX-fp8 GEMM + ll epilogue ----------------
// 8 waves as 4m x 2n: wave (wr,wc) owns rows wr*64..+63 (4 m-frags) x cols
// wc*144..+143 (9 n-frags). acc = 4*9*4 = 144 regs.
// A: per-tile direct global loads (2 dwordx4/frag, issued BEFORE B staging so
// the compiler's wait-for-A is a counted vmcnt and B prefetch stays in flight).
// B: double-buffered LDS; stage(t+1) issued during tile t; vmcnt(0)+barrier
// once per tile.
#define MFMA_COL(nt, bv)                                              \
  do {                                                                \
    acc[0][nt] = __builtin_amdgcn_mfma_scale_f32_16x16x128_f8f6f4(    \
        a0, bv, acc[0][nt], 0, 0, 0, 0x7f7f7f7f, 0, 0x7f7f7f7f);      \
    acc[1][nt] = __builtin_amdgcn_mfma_scale_f32_16x16x128_f8f6f4(    \
        a1, bv, acc[1][nt], 0, 0, 0, 0x7f7f7f7f, 0, 0x7f7f7f7f);      \
    acc[2][nt] = __builtin_amdgcn_mfma_scale_f32_16x16x128_f8f6f4(    \
        a2, bv, acc[2][nt], 0, 0, 0, 0x7f7f7f7f, 0, 0x7f7f7f7f);      \
    acc[3][nt] = __builtin_amdgcn_mfma_scale_f32_16x16x128_f8f6f4(    \
        a3, bv, acc[3][nt], 0, 0, 0, 0x7f7f7f7f, 0, 0x7f7f7f7f);      \
  } while (0)

__global__ __launch_bounds__(512, 1) void gemm_ll(
    const unsigned char* __restrict__ xq, const unsigned char* __restrict__ Gq,
    const float* __restrict__ Minv, const float* __restrict__ offk,
    const float* __restrict__ logpi, const float* __restrict__ logdetPsi,
    const float* __restrict__ xPx, float* __restrict__ ll) {
  __shared__ __align__(16) char smem[LDS_TOT];
  float* sMinv = (float*)(smem + LDS_MINV);    // [32][65]
  float* sOff  = (float*)(smem + LDS_OFFC);    // [32]
  float* Cs    = (float*)(smem + LDS_CS);      // 8 x [16][148]

  int t = threadIdx.x, lane = t & 63, w = t >> 6;
  int wr = w >> 1, wc = w & 1;
  int m0 = blockIdx.y * BM;
  int n0 = blockIdx.x * BN;
  int comp0 = blockIdx.x * 32;

  // load Minv into padded-stride LDS (32 comps)
  for (int i = t; i < 2048; i += 512) {
    int cl = i >> 6, idx = i & 63;
    sMinv[cl * 65 + idx] = Minv[(size_t)comp0 * 64 + i];
  }
  if (t < 32)
    sOff[t] = offk[comp0 + t] + logpi[comp0 + t] - 0.5f * logdetPsi[0];

  f32x4 acc[4][9];
  f32x4 zero = {0.f, 0.f, 0.f, 0.f};
#pragma unroll
  for (int mt = 0; mt < 4; mt++)
#pragma unroll
    for (int nt = 0; nt < 9; nt++) acc[mt][nt] = zero;

  // staging geometry: each 1KB wave-load covers 8 rows x 8 chunks of 16B
  int rr  = lane >> 3;        // row within 8-row group
  int cph = lane & 7;         // physical chunk slot in LDS
  int csw = cph ^ rr;         // swizzled global chunk index
  // fragment-read geometry
  int quad = lane >> 4, r16 = lane & 15;
  int s8 = r16 & 7;
  // per-wave LDS row base byte offset for B (add frag idx * 2048 and buffer)
  const int boff = (wc * 144 + r16) * 128;
  // A global base: this lane's row + 32B k-chunk (add k0 and frag*16*Dd)
  const char* abase =
      (const char*)xq + (size_t)(m0 + wr * 64 + r16) * Dd + quad * 32;

  // All 8 waves stage B (36 x 1KB wave-loads per tile: 4+4+4+4+5+5+5+5)
  auto stage = [&](int buf, int k0) {
    char* dst = smem + LDS_BS + buf * 36864;
    if (w < 4) {
#pragma unroll
      for (int i = 0; i < 4; ++i) {
        int j = w * 4 + i;
        glds16(Gq + (size_t)(n0 + j * 8 + rr) * Dd + k0 + csw * 16,
               dst + j * 1024);
      }
    } else {
#pragma unroll
      for (int i = 0; i < 5; ++i) {
        int j = 16 + (w - 4) * 5 + i;
        glds16(Gq + (size_t)(n0 + j * 8 + rr) * Dd + k0 + csw * 16,
               dst + j * 1024);
      }
    }
  };

  // prologue: stage tile 0 into buffer 0, drain once
  stage(0, 0);
  asm volatile("s_waitcnt vmcnt(0) lgkmcnt(0)" ::: "memory");
  BARRIER();

#pragma unroll 1
  for (int tt = 0; tt < NT; ++tt) {
    int cur = tt & 1;
    const char* Bb = smem + LDS_BS + cur * 36864;
    int k0 = tt * BK;
    // A-frags from global, issued FIRST (counted-vmcnt wait before 1st MFMA)
    i32x8v a0 = ld_ga(abase + k0);
    i32x8v a1 = ld_ga(abase + 32768 + k0);   // +16*Dd rows
    i32x8v a2 = ld_ga(abase + 65536 + k0);
    i32x8v a3 = ld_ga(abase + 98304 + k0);
    // issue next tile's B staging -> in flight across this tile's MFMAs
    if (tt < NT - 1) stage(cur ^ 1, k0 + BK);
    // compute tile tt: compiler interleaves ds_read/MFMA with fine lgkmcnt
#pragma unroll
    for (int nt = 0; nt < 9; ++nt) {
      i32x8v bv = ld_frag(Bb + boff + nt * 2048, quad, s8);
      MFMA_COL(nt, bv);
    }
    // B(t+1) landed (issued ~2500cy ago); then cross-wave barrier
    asm volatile("s_waitcnt vmcnt(0)" ::: "memory");
    BARRIER();
  }

  // Hoisted Minv upper-triangle (comp = wc*16 + r16, invariant). 0.5 on diag.
  float P[36];
  {
    const float* Mi = sMinv + (wc * 16 + r16) * 65;
    int c = 0;
#pragma unroll
    for (int i2 = 0; i2 < 8; i2++) {
      P[c++] = 0.5f * Mi[i2 * 8 + i2];
#pragma unroll
      for (int j2 = i2 + 1; j2 < 8; j2++) P[c++] = Mi[i2 * 8 + j2];
    }
  }
  float offc = sOff[wc * 16 + r16];

  // Epilogue: per-wave private Cs strip (own LDS region, no overlay)
  float* myC = Cs + w * (16 * 148);
#pragma unroll
  for (int mt = 0; mt < 4; ++mt) {
#pragma unroll
    for (int nt = 0; nt < 9; ++nt) {
#pragma unroll
      for (int r = 0; r < 4; r++) {
        myC[(quad * 4 + r) * 148 + nt * 16 + r16] = acc[mt][nt][r];
      }
    }
#pragma unroll
    for (int i = 0; i < 4; i++) {
      int row_l = quad + 4 * i;
      int b = m0 + wr * 64 + mt * 16 + row_l;
      const float* cp = myC + row_l * 148 + r16 * 9;
      float u[8];
#pragma unroll
      for (int j = 0; j < 8; j++) u[j] = cp[j] * INV_UW;   // unfold SX*SW
      float s = cp[8] * INV_UG;                            // unfold SX*SG
      float tq = 0.f;
      int c = 0;
#pragma unroll
      for (int i2 = 0; i2 < 8; i2++) {
        float s2 = P[c++] * u[i2];
#pragma unroll
        for (int j2 = i2 + 1; j2 < 8; j2++) s2 += P[c++] * u[j2];
        tq += u[i2] * s2;
      }
      ll[(size_t)b * Kk + comp0 + wc * 16 + r16] = offc + s + tq - 0.5f * xPx[b];
    }
  }
}

// ---------------- Kernel E1: logsumexp per row -> block partials ----------------
__global__ __launch_bounds__(256) void lse_rows(
    const float* __restrict__ ll, float* __restrict__ part) {
  int t = threadIdx.x, lane = t & 63, w = t >> 6;
  int b = blockIdx.x * 4 + w;
  const float* row = ll + (size_t)b * Kk;
  float v[8];
  float mx = -3.4e38f;
#pragma unroll
  for (int i = 0; i < 8; i++) { v[i] = row[lane + 64 * i]; mx = fmaxf(mx, v[i]); }
#pragma unroll
  for (int o = 32; o; o >>= 1) mx = fmaxf(mx, __shfl_xor(mx, o, 64));
  float se = 0.f;
#pragma unroll
  for (int i = 0; i < 8; i++) se += expf(v[i] - mx);
#pragma unroll
  for (int o = 32; o; o >>= 1) se += __shfl_xor(se, o, 64);
  __shared__ float r4[4];
  if (lane == 0) r4[w] = -(mx + logf(se));
  __syncthreads();
  if (t == 0) part[blockIdx.x] = r4[0] + r4[1] + r4[2] + r4[3];
}

// ---------------- Kernel E2: final mean ----------------
__global__ __launch_bounds__(256) void final_mean(
    const float* __restrict__ part, float* __restrict__ out) {
  int t = threadIdx.x, lane = t & 63, w = t >> 6;
  float acc = 0.f;
  for (int i = t; i < 2048; i += 256) acc += part[i];
#pragma unroll
  for (int o = 32; o; o >>= 1) acc += __shfl_down(acc, o, 64);
  __shared__ float r4[4];
  if (lane == 0) r4[w] = acc;
  __syncthreads();
  if (t == 0) out[0] = (r4[0] + r4[1] + r4[2] + r4[3]) * (1.0f / 8192.0f);
}

extern "C" void kernel_launch(void* const* d_in, const int* in_sizes, int n_in,
                              void* d_out, int out_size, void* d_ws, size_t ws_size,
                              hipStream_t stream) {
  const float* x         = (const float*)d_in[0];
  const float* mu        = (const float*)d_in[1];
  const float* dir_raw   = (const float*)d_in[2];
  const float* scale_rho = (const float*)d_in[3];
  const float* psi_rho   = (const float*)d_in[4];
  const float* pi_logits = (const float*)d_in[5];
  float* out = (float*)d_out;
  char* ws = (char*)d_ws;

  float* psi_inv          = (float*)(ws + OFF_PSI);
  float* logdetPsi        = (float*)(ws + OFF_LDP);
  float* logpi            = (float*)(ws + OFF_LOGPI);
  float* offk             = (float*)(ws + OFF_OFFK);
  float* Minv             = (float*)(ws + OFF_MINV);
  float* xPx              = (float*)(ws + OFF_XPX);
  unsigned char* xq       = (unsigned char*)(ws + OFF_XBF);
  unsigned char* Gq       = (unsigned char*)(ws + OFF_GT);
  float* ll               = (float*)(ws + OFF_LL);
  float* part             = (float*)(ws + OFF_PART);

  prep_psi<<<1, 256, 0, stream>>>(psi_rho, pi_logits, psi_inv, logdetPsi, logpi);
  prep_all<<<Kk + Bn, 256, 0, stream>>>(x, mu, dir_raw, scale_rho, psi_inv,
                                        offk, Minv, Gq, xq, xPx);
  dim3 g(Nn / BN, Bn / BM);  // (16, 32)
  gemm_ll<<<g, 512, 0, stream>>>(xq, Gq, Minv, offk, logpi, logdetPsi, xPx, ll);
  lse_rows<<<Bn / 4, 256, 0, stream>>>(ll, part);
  final_mean<<<1, 256, 0, stream>>>(part, out);
}

// Round 5
// 220.869 us; speedup vs baseline: 1.2036x; 1.2036x over previous
//
#include <hip/hip_runtime.h>

// Problem constants
constexpr int Bn = 8192;   // batch
constexpr int Dd = 2048;   // dims
constexpr int Kk = 512;    // components
constexpr int Qq = 8;      // factors
constexpr int Nn = Kk * 9; // GEMM N: 8 PinvW cols + 1 g col per component = 4608
constexpr float DLOG2PI = 3763.9722f; // D * log(2*pi)

// GEMM tiling: 256x288 tile (32 comps), BK=128 fp8 bytes, 8 waves (4m x 2n).
// Double-buffered LDS for A and B; per tile: stage(t+1) first, then a fully
// MANUAL software pipeline: inline-asm ds_read_b128 with hand-counted
// lgkmcnt(4) waits (depth-3 B-frag ring) so reads run ~400cy ahead of use.
// vmcnt(0)+raw s_barrier once per tile.
constexpr int BM = 256, BN = 288, BK = 128;
constexpr int NT = Dd / BK;  // 16 K-tiles

// Quantization scales (powers of 2, folded out in the epilogue)
constexpr float SX = 16.f;   // x
constexpr float SW = 64.f;   // W columns (q<8)
constexpr float SG = 16.f;   // g column  (q==8)
constexpr float INV_UW = 1.f / (16.f * 64.f);  // u = cp/1024
constexpr float INV_UG = 1.f / (16.f * 16.f);  // s = cp/256

// Workspace layout (bytes)
constexpr size_t OFF_PSI   = 0;          // psi_inv: D*4
constexpr size_t OFF_LDP   = 8192;       // logdetPsi scalar
constexpr size_t OFF_LOGPI = 8448;       // K*4
constexpr size_t OFF_OFFK  = 10752;      // K*4
constexpr size_t OFF_MINV  = 13056;      // K*64*4
constexpr size_t OFF_XPX   = 144384;     // B*4
constexpr size_t OFF_XBF   = 177408;     // x fp8: B*D*1
constexpr size_t OFF_GT    = 33731840;   // G fp8: N*D*1  (Gq[n][d], k-contig rows)
constexpr size_t OFF_LL    = 52606208;   // B*K*4
constexpr size_t OFF_PART  = 69383424;   // 2048*4

// LDS layout for gemm_ll (bytes) — R2 layout (A staged again)
constexpr int LDS_AS   = 0;        // 2 x 256*128 = 65536
constexpr int LDS_BS   = 65536;    // 2 x 288*128 = 73728 -> end 139264
constexpr int LDS_MINV = 139264;   // 32*65*4 = 8320
constexpr int LDS_OFFC = 147584;   // 32*4
constexpr int LDS_TOT  = 147712;   // <= 160 KiB

typedef float f32x4 __attribute__((ext_vector_type(4)));
typedef int   i32x4v __attribute__((ext_vector_type(4)));
typedef int   i32x8v __attribute__((ext_vector_type(8)));
typedef __attribute__((address_space(3))) char lds_char;

__device__ inline float softplusf(float x) {
  return fmaxf(x, 0.f) + log1pf(expf(-fabsf(x)));
}
__device__ inline unsigned short f2bf(float x) {
  unsigned int u = __builtin_bit_cast(unsigned int, x);
  u = (u + 0x7fffu + ((u >> 16) & 1u)) >> 16;
  return (unsigned short)u;
}
__device__ inline unsigned int pack2(float a, float b) {
  return (unsigned int)f2bf(a) | ((unsigned int)f2bf(b) << 16);
}
__device__ inline float bf2f(unsigned int u16) {
  unsigned int v = u16 << 16;
  return __builtin_bit_cast(float, v);
}
// single float -> fp8 e4m3 (OCP on gfx950), RNE
__device__ inline unsigned char f2fp8(float x) {
  int v = __builtin_amdgcn_cvt_pk_fp8_f32(x, 0.f, 0, false);
  return (unsigned char)(v & 0xff);
}
// async global->LDS, 16B per lane; LDS dest is wave-uniform base + lane*16
__device__ inline void glds16(const unsigned char* g, char* l) {
  __builtin_amdgcn_global_load_lds(
      (const __attribute__((address_space(1))) unsigned int*)g,
      (__attribute__((address_space(3))) unsigned int*)l, 16, 0, 0);
}

// Raw barrier (no compiler vmcnt(0) drain, unlike __syncthreads)
#define BARRIER()                                   \
  do {                                              \
    asm volatile("" ::: "memory");                  \
    __builtin_amdgcn_s_barrier();                   \
    asm volatile("" ::: "memory");                  \
  } while (0)

// Two ds_read_b128 (lo/hi 16B of a 32B k-chunk) with compile-time offset.
// Volatile asm keeps program order among reads and waits.
#define DSR2(LO, HI, PL, PH, IMMS)                                    \
  asm volatile("ds_read_b128 %0, %2 offset:" IMMS "\n\t"              \
               "ds_read_b128 %1, %3 offset:" IMMS                     \
               : "=&v"(LO), "=&v"(HI)                                 \
               : "v"(PL), "v"(PH));

// Counted lgkm wait + full scheduling fence (guide rule #18)
#define WAITLG(NS)                                                    \
  do {                                                                \
    asm volatile("s_waitcnt lgkmcnt(" NS ")" ::: "memory");           \
    __builtin_amdgcn_sched_barrier(0);                                \
  } while (0)

#define CAT8(D, LO, HI)                                               \
  do { D[0]=LO[0];D[1]=LO[1];D[2]=LO[2];D[3]=LO[3];                   \
       D[4]=HI[0];D[5]=HI[1];D[6]=HI[2];D[7]=HI[3]; } while (0)

// ---------------- Kernel A: psi_inv, logdetPsi, log_pi (1 block) ----------------
__global__ __launch_bounds__(256) void prep_psi(
    const float* __restrict__ psi_rho, const float* __restrict__ pi_logits,
    float* __restrict__ psi_inv, float* __restrict__ logdetPsi,
    float* __restrict__ logpi) {
  __shared__ float red[256];
  int t = threadIdx.x;
  float acc = 0.f;
  for (int d = t; d < Dd; d += 256) {
    float p = softplusf(psi_rho[d]) + 1e-5f;
    psi_inv[d] = 1.f / p;
    acc += logf(p);
  }
  red[t] = acc;
  __syncthreads();
  for (int s = 128; s > 0; s >>= 1) { if (t < s) red[t] += red[t + s]; __syncthreads(); }
  if (t == 0) *logdetPsi = red[0];
  __syncthreads();
  float mx = -3.4e38f;
  for (int i = t; i < Kk; i += 256) mx = fmaxf(mx, pi_logits[i]);
  red[t] = mx;
  __syncthreads();
  for (int s = 128; s > 0; s >>= 1) { if (t < s) red[t] = fmaxf(red[t], red[t + s]); __syncthreads(); }
  mx = red[0];
  __syncthreads();
  float se = 0.f;
  for (int i = t; i < Kk; i += 256) se += expf(pi_logits[i] - mx);
  red[t] = se;
  __syncthreads();
  for (int s = 128; s > 0; s >>= 1) { if (t < s) red[t] += red[t + s]; __syncthreads(); }
  float lse = mx + logf(red[0]);
  for (int i = t; i < Kk; i += 256) logpi[i] = pi_logits[i] - lse;
}

// ---------------- Fused prep kernel ----------------
// lower-tri packed index (row i >= col j)
#define TRI(i, j) ((i) * ((i) + 1) / 2 + (j))

__global__ __launch_bounds__(256) void prep_all(
    const float* __restrict__ x, const float* __restrict__ mu,
    const float* __restrict__ dir_raw, const float* __restrict__ scale_rho,
    const float* __restrict__ psi_inv,
    float* __restrict__ offk, float* __restrict__ Minv,
    unsigned char* __restrict__ Gq, unsigned char* __restrict__ xq,
    float* __restrict__ xPx) {
  __shared__ unsigned short sDir[Dd * 8];  // bf16 pw*dir, 32 KB (k-work)
  __shared__ float sPwmd[Dd];              // f32 pw*mu (k-work; scratch for x-work)
  __shared__ float redk[4 * 53];
  __shared__ float R[53];
  __shared__ float sAl[8], sAh[8];
  __shared__ float sLt[36], sLdt[8];       // packed Cholesky L + inv diag

  int bid = blockIdx.x;
  int t = threadIdx.x, lane = t & 63, w = t >> 6;

  if (bid >= Kk) {
    // ---- x-work: row b -> fp8 (x16) + xT Psi^-1 x ----
    int b = bid - Kk;
    const float4* xr = (const float4*)(x + (size_t)b * Dd);
    const float4* pr = (const float4*)psi_inv;
    float4 v0 = xr[2 * t], v1 = xr[2 * t + 1];
    float4 p0 = pr[2 * t], p1 = pr[2 * t + 1];
    float acc = v0.x * v0.x * p0.x + v0.y * v0.y * p0.y + v0.z * v0.z * p0.z + v0.w * v0.w * p0.w
              + v1.x * v1.x * p1.x + v1.y * v1.y * p1.y + v1.z * v1.z * p1.z + v1.w * v1.w * p1.w;
    unsigned int q0 = (unsigned int)__builtin_amdgcn_cvt_pk_fp8_f32(SX * v0.x, SX * v0.y, 0, false);
    q0 = (unsigned int)__builtin_amdgcn_cvt_pk_fp8_f32(SX * v0.z, SX * v0.w, (int)q0, true);
    unsigned int q1 = (unsigned int)__builtin_amdgcn_cvt_pk_fp8_f32(SX * v1.x, SX * v1.y, 0, false);
    q1 = (unsigned int)__builtin_amdgcn_cvt_pk_fp8_f32(SX * v1.z, SX * v1.w, (int)q1, true);
    uint2 o; o.x = q0; o.y = q1;
    *(uint2*)(xq + (size_t)b * Dd + t * 8) = o;
#pragma unroll
    for (int s2 = 32; s2; s2 >>= 1) acc += __shfl_down(acc, s2, 64);
    float* r4 = sPwmd;
    if (lane == 0) r4[w] = acc;
    __syncthreads();
    if (t == 0) xPx[b] = r4[0] + r4[1] + r4[2] + r4[3];
    return;
  }

  // ---- k-work ----
  int k = bid;
  float vals[53];
#pragma unroll
  for (int i = 0; i < 53; i++) vals[i] = 0.f;
  const float4* dirp = (const float4*)(dir_raw + (size_t)k * Dd * Qq);
  for (int d = t; d < Dd; d += 256) {
    float4 da = dirp[d * 2], db = dirp[d * 2 + 1];
    float dir8[8] = {da.x, da.y, da.z, da.w, db.x, db.y, db.z, db.w};
    float pw = psi_inv[d];
    float md = mu[(size_t)k * Dd + d];
    int c = 0;
#pragma unroll
    for (int i = 0; i < 8; i++) {
      float dip = dir8[i] * pw;
#pragma unroll
      for (int j = 0; j < 8; j++) {
        if (j < i) continue;
        vals[c] += dip * dir8[j]; c++;
      }
    }
#pragma unroll
    for (int q = 0; q < 8; q++) vals[36 + q] += dir8[q] * dir8[q];
    float mp = md * pw;
#pragma unroll
    for (int q = 0; q < 8; q++) vals[44 + q] += mp * dir8[q];
    vals[52] += md * mp;
    uint4 pk;
    pk.x = pack2(pw * dir8[0], pw * dir8[1]);
    pk.y = pack2(pw * dir8[2], pw * dir8[3]);
    pk.z = pack2(pw * dir8[4], pw * dir8[5]);
    pk.w = pack2(pw * dir8[6], pw * dir8[7]);
    *(uint4*)(sDir + d * 8) = pk;
    sPwmd[d] = mp;
  }
#pragma unroll
  for (int v = 0; v < 53; v++) {
    float val = vals[v];
#pragma unroll
    for (int o = 32; o; o >>= 1) val += __shfl_down(val, o, 64);
    if (lane == 0) redk[w * 53 + v] = val;
  }
  __syncthreads();
  if (t < 53) R[t] = redk[t] + redk[53 + t] + redk[106 + t] + redk[159 + t];
  __syncthreads();
  if (t == 0) {
    float Sf[8][8];
    {
      int c2 = 0;
#pragma unroll
      for (int i = 0; i < 8; i++) {
#pragma unroll
        for (int j = 0; j < 8; j++) {
          if (j < i) continue;
          float v = R[c2++]; Sf[i][j] = v; Sf[j][i] = v;
        }
      }
    }
    float alpha[8];
#pragma unroll
    for (int q = 0; q < 8; q++) {
      float nr = fmaxf(sqrtf(R[36 + q]), 1e-5f);
      alpha[q] = softplusf(scale_rho[(size_t)k * 8 + q]) / nr;
    }
    float Mm[8][8];
#pragma unroll
    for (int i = 0; i < 8; i++)
#pragma unroll
      for (int j = 0; j < 8; j++)
        Mm[i][j] = alpha[i] * alpha[j] * Sf[i][j] + (i == j ? 1.f : 0.f);
    float L[8][8], Ld[8];
#pragma unroll
    for (int i = 0; i < 8; i++) {
#pragma unroll
      for (int j = 0; j < 8; j++) {
        if (j > i) continue;
        float s2 = Mm[i][j];
#pragma unroll
        for (int p = 0; p < 8; p++) { if (p < j) s2 -= L[i][p] * L[j][p]; }
        if (i == j) { L[i][i] = sqrtf(s2); Ld[i] = 1.f / L[i][i]; }
        else        L[i][j] = s2 * Ld[j];
      }
    }
    float logdetM = 0.f;
#pragma unroll
    for (int i = 0; i < 8; i++) logdetM += 2.f * logf(L[i][i]);
    float wv[8];
#pragma unroll
    for (int q = 0; q < 8; q++) wv[q] = alpha[q] * R[44 + q];
    float y[8], h[8];
#pragma unroll
    for (int i = 0; i < 8; i++) {
      float s2 = wv[i];
#pragma unroll
      for (int p = 0; p < 8; p++) { if (p < i) s2 -= L[i][p] * y[p]; }
      y[i] = s2 * Ld[i];
    }
#pragma unroll
    for (int i = 7; i >= 0; i--) {
      float s2 = y[i];
#pragma unroll
      for (int p = 0; p < 8; p++) { if (p > i) s2 -= L[p][i] * h[p]; }
      h[i] = s2 * Ld[i];
    }
    float cc = R[52];
#pragma unroll
    for (int q = 0; q < 8; q++) cc -= wv[q] * h[q];
    // publish L, Ld for the parallel per-column Minv solves
    {
      int c3 = 0;
#pragma unroll
      for (int i = 0; i < 8; i++)
#pragma unroll
        for (int j = 0; j < 8; j++) { if (j <= i) sLt[c3++] = L[i][j]; }
#pragma unroll
      for (int i = 0; i < 8; i++) sLdt[i] = Ld[i];
    }
    offk[k] = -0.5f * (DLOG2PI + logdetM + cc);
#pragma unroll
    for (int q = 0; q < 8; q++) { sAl[q] = alpha[q]; sAh[q] = alpha[q] * h[q]; }
  }
  __syncthreads();
  // Minv: 8 independent column solves, one per thread
  if (t < 8) {
    int col = t;
    float yy[8], z[8];
#pragma unroll
    for (int i = 0; i < 8; i++) {
      float s2 = (i == col) ? 1.f : 0.f;
#pragma unroll
      for (int p = 0; p < 8; p++) { if (p < i) s2 -= sLt[TRI(i, p)] * yy[p]; }
      yy[i] = s2 * sLdt[i];
    }
#pragma unroll
    for (int i = 7; i >= 0; i--) {
      float s2 = yy[i];
#pragma unroll
      for (int p = 0; p < 8; p++) { if (p > i) s2 -= sLt[TRI(p, i)] * z[p]; }
      z[i] = s2 * sLdt[i];
    }
#pragma unroll
    for (int r2 = 0; r2 < 8; r2++) Minv[(size_t)k * 64 + r2 * 8 + col] = z[r2];
  }
  float al[8], ah[8];
#pragma unroll
  for (int q = 0; q < 8; q++) { al[q] = sAl[q]; ah[q] = sAh[q]; }
  for (int d = t; d < Dd; d += 256) {
    uint4 pk = *(const uint4*)(sDir + d * 8);
    float pd[8];
    pd[0] = bf2f(pk.x & 0xffffu); pd[1] = bf2f(pk.x >> 16);
    pd[2] = bf2f(pk.y & 0xffffu); pd[3] = bf2f(pk.y >> 16);
    pd[4] = bf2f(pk.z & 0xffffu); pd[5] = bf2f(pk.z >> 16);
    pd[6] = bf2f(pk.w & 0xffffu); pd[7] = bf2f(pk.w >> 16);
    float gs = 0.f;
#pragma unroll
    for (int q = 0; q < 8; q++) {
      Gq[((size_t)(k * 9 + q)) * Dd + d] = f2fp8(SW * al[q] * pd[q]);
      gs += ah[q] * pd[q];
    }
    Gq[((size_t)(k * 9 + 8)) * Dd + d] = f2fp8(SG * (sPwmd[d] - gs));
  }
}

// ---------------- Kernel D: fused MX-fp8 GEMM + ll epilogue ----------------
// 8 waves as 4m x 2n: wave (wr,wc) owns rows wr*64..+63 (4 m-frags) x cols
// wc*144..+143 (9 n-frags). acc = 4*9*4 = 144 regs.
// Manual pipeline per tile: issue stage(t+1); asm-read a0..a3,b0,b1,b2;
// then 9 steps of {lgkmcnt(4) [counted], 4 MFMA, issue b(nt+3)} with a
// depth-3 B ring; vmcnt(0)+barrier once per tile.
#define MFMA_COL(nt, bv)                                              \
  do {                                                                \
    acc[0][nt] = __builtin_amdgcn_mfma_scale_f32_16x16x128_f8f6f4(    \
        a0, bv, acc[0][nt], 0, 0, 0, 0x7f7f7f7f, 0, 0x7f7f7f7f);      \
    acc[1][nt] = __builtin_amdgcn_mfma_scale_f32_16x16x128_f8f6f4(    \
        a1, bv, acc[1][nt], 0, 0, 0, 0x7f7f7f7f, 0, 0x7f7f7f7f);      \
    acc[2][nt] = __builtin_amdgcn_mfma_scale_f32_16x16x128_f8f6f4(    \
        a2, bv, acc[2][nt], 0, 0, 0, 0x7f7f7f7f, 0, 0x7f7f7f7f);      \
    acc[3][nt] = __builtin_amdgcn_mfma_scale_f32_16x16x128_f8f6f4(    \
        a3, bv, acc[3][nt], 0, 0, 0, 0x7f7f7f7f, 0, 0x7f7f7f7f);      \
  } while (0)

__global__ __launch_bounds__(512, 1) void gemm_ll(
    const unsigned char* __restrict__ xq, const unsigned char* __restrict__ Gq,
    const float* __restrict__ Minv, const float* __restrict__ offk,
    const float* __restrict__ logpi, const float* __restrict__ logdetPsi,
    const float* __restrict__ xPx, float* __restrict__ ll) {
  __shared__ __align__(16) char smem[LDS_TOT];
  float* Cs    = (float*)smem;                 // epilogue union: 8 x [16][148]
  float* sMinv = (float*)(smem + LDS_MINV);    // [32][65]
  float* sOff  = (float*)(smem + LDS_OFFC);    // [32]
  lds_char* sm3 = (lds_char*)smem;

  int t = threadIdx.x, lane = t & 63, w = t >> 6;
  int wr = w >> 1, wc = w & 1;
  int m0 = blockIdx.y * BM;
  int n0 = blockIdx.x * BN;
  int comp0 = blockIdx.x * 32;

  // load Minv into padded-stride LDS (32 comps)
  for (int i = t; i < 2048; i += 512) {
    int cl = i >> 6, idx = i & 63;
    sMinv[cl * 65 + idx] = Minv[(size_t)comp0 * 64 + i];
  }
  if (t < 32)
    sOff[t] = offk[comp0 + t] + logpi[comp0 + t] - 0.5f * logdetPsi[0];

  f32x4 acc[4][9];
  f32x4 zero = {0.f, 0.f, 0.f, 0.f};
#pragma unroll
  for (int mt = 0; mt < 4; mt++)
#pragma unroll
    for (int nt = 0; nt < 9; nt++) acc[mt][nt] = zero;

  // staging geometry: each 1KB wave-load covers 8 rows x 8 chunks of 16B
  int rr  = lane >> 3;        // row within 8-row group
  int cph = lane & 7;         // physical chunk slot in LDS
  int csw = cph ^ rr;         // swizzled global chunk index
  // fragment-read geometry
  int quad = lane >> 4, r16 = lane & 15;
  int s8 = r16 & 7;
  int clo = (((2 * quad)     ^ s8) * 16);  // lo 16B of 32B k-chunk (swizzled)
  int chi = (((2 * quad + 1) ^ s8) * 16);  // hi 16B
  // per-wave LDS row base byte offsets (add frag idx * 2048 and buffer base)
  const int aoff = (wr * 64 + r16) * 128;
  const int boff = (wc * 144 + r16) * 128;

  // waves 0-3 stage A (8 x 1KB loads/tile), waves 4-7 stage B (9 loads/tile).
  auto stage = [&](int buf, int k0) {
    if (w < 4) {
      char* dst = smem + LDS_AS + buf * 32768 + w * 8192;
      const unsigned char* src =
          xq + (size_t)(m0 + w * 64 + rr) * Dd + k0 + csw * 16;
#pragma unroll
      for (int i = 0; i < 8; ++i)
        glds16(src + (size_t)i * 8 * Dd, dst + i * 1024);
    } else {
      int w4 = w - 4;
      char* dst = smem + LDS_BS + buf * 36864 + w4 * 9216;
      const unsigned char* src =
          Gq + (size_t)(n0 + w4 * 72 + rr) * Dd + k0 + csw * 16;
#pragma unroll
      for (int i = 0; i < 9; ++i)
        glds16(src + (size_t)i * 8 * Dd, dst + i * 1024);
    }
  };

  // prologue: stage tile 0 into buffer 0, drain everything once
  stage(0, 0);
  asm volatile("s_waitcnt vmcnt(0) lgkmcnt(0)" ::: "memory");
  BARRIER();

#pragma unroll 1
  for (int tt = 0; tt < NT; ++tt) {
    int cur = tt & 1;
    lds_char* pAl = sm3 + (LDS_AS + cur * 32768) + aoff + clo;
    lds_char* pAh = sm3 + (LDS_AS + cur * 32768) + aoff + chi;
    lds_char* pBl = sm3 + (LDS_BS + cur * 36864) + boff + clo;
    lds_char* pBh = sm3 + (LDS_BS + cur * 36864) + boff + chi;
    // issue next tile's staging FIRST (vmcnt domain, doesn't touch lgkm)
    if (tt < NT - 1) stage(cur ^ 1, (tt + 1) * BK);
    // asm reads: A frags (8 ds ops) + B ring b0,b1,b2 (6 ds ops)
    i32x4v a0l, a0h, a1l, a1h, a2l, a2h, a3l, a3h;
    i32x4v bXl, bXh, bYl, bYh, bZl, bZh;
    DSR2(a0l, a0h, pAl, pAh, "0")
    DSR2(a1l, a1h, pAl, pAh, "2048")
    DSR2(a2l, a2h, pAl, pAh, "4096")
    DSR2(a3l, a3h, pAl, pAh, "6144")
    DSR2(bXl, bXh, pBl, pBh, "0")
    DSR2(bYl, bYh, pBl, pBh, "2048")
    DSR2(bZl, bZh, pBl, pBh, "4096")
    i32x8v a0, a1, a2, a3, bq;
    // step 0: wait until only b1,b2 outstanding -> a*, b0 ready
    WAITLG("4");
    CAT8(a0, a0l, a0h); CAT8(a1, a1l, a1h);
    CAT8(a2, a2l, a2h); CAT8(a3, a3l, a3h);
    CAT8(bq, bXl, bXh);
    MFMA_COL(0, bq);
    DSR2(bXl, bXh, pBl, pBh, "6144")      // b3 -> X
    WAITLG("4"); CAT8(bq, bYl, bYh); MFMA_COL(1, bq);
    DSR2(bYl, bYh, pBl, pBh, "8192")      // b4 -> Y
    WAITLG("4"); CAT8(bq, bZl, bZh); MFMA_COL(2, bq);
    DSR2(bZl, bZh, pBl, pBh, "10240")     // b5 -> Z
    WAITLG("4"); CAT8(bq, bXl, bXh); MFMA_COL(3, bq);
    DSR2(bXl, bXh, pBl, pBh, "12288")     // b6 -> X
    WAITLG("4"); CAT8(bq, bYl, bYh); MFMA_COL(4, bq);
    DSR2(bYl, bYh, pBl, pBh, "14336")     // b7 -> Y
    WAITLG("4"); CAT8(bq, bZl, bZh); MFMA_COL(5, bq);
    DSR2(bZl, bZh, pBl, pBh, "16384")     // b8 -> Z
    WAITLG("4"); CAT8(bq, bXl, bXh); MFMA_COL(6, bq);
    WAITLG("2"); CAT8(bq, bYl, bYh); MFMA_COL(7, bq);
    WAITLG("0"); CAT8(bq, bZl, bZh); MFMA_COL(8, bq);
    // own prefetch glds landed (issued a full tile ago); cross-wave barrier
    asm volatile("s_waitcnt vmcnt(0)" ::: "memory");
    BARRIER();
  }

  // Hoisted Minv upper-triangle (comp = wc*16 + r16, invariant). 0.5 on diag.
  float P[36];
  {
    const float* Mi = sMinv + (wc * 16 + r16) * 65;
    int c = 0;
#pragma unroll
    for (int i2 = 0; i2 < 8; i2++) {
      P[c++] = 0.5f * Mi[i2 * 8 + i2];
#pragma unroll
      for (int j2 = i2 + 1; j2 < 8; j2++) P[c++] = Mi[i2 * 8 + j2];
    }
  }
  float offc = sOff[wc * 16 + r16];

  // Epilogue: per-wave private Cs strip (overlays staging LDS; the loop's
  // final barrier guarantees all staging reads are done).
  float* myC = Cs + w * (16 * 148);
#pragma unroll
  for (int mt = 0; mt < 4; ++mt) {
#pragma unroll
    for (int nt = 0; nt < 9; ++nt) {
#pragma unroll
      for (int r = 0; r < 4; r++) {
        myC[(quad * 4 + r) * 148 + nt * 16 + r16] = acc[mt][nt][r];
      }
    }
#pragma unroll
    for (int i = 0; i < 4; i++) {
      int row_l = quad + 4 * i;
      int b = m0 + wr * 64 + mt * 16 + row_l;
      const float* cp = myC + row_l * 148 + r16 * 9;
      float u[8];
#pragma unroll
      for (int j = 0; j < 8; j++) u[j] = cp[j] * INV_UW;   // unfold SX*SW
      float s = cp[8] * INV_UG;                            // unfold SX*SG
      float tq = 0.f;
      int c = 0;
#pragma unroll
      for (int i2 = 0; i2 < 8; i2++) {
        float s2 = P[c++] * u[i2];
#pragma unroll
        for (int j2 = i2 + 1; j2 < 8; j2++) s2 += P[c++] * u[j2];
        tq += u[i2] * s2;
      }
      ll[(size_t)b * Kk + comp0 + wc * 16 + r16] = offc + s + tq - 0.5f * xPx[b];
    }
  }
}

// ---------------- Kernel E1: logsumexp per row -> block partials ----------------
__global__ __launch_bounds__(256) void lse_rows(
    const float* __restrict__ ll, float* __restrict__ part) {
  int t = threadIdx.x, lane = t & 63, w = t >> 6;
  int b = blockIdx.x * 4 + w;
  const float* row = ll + (size_t)b * Kk;
  float v[8];
  float mx = -3.4e38f;
#pragma unroll
  for (int i = 0; i < 8; i++) { v[i] = row[lane + 64 * i]; mx = fmaxf(mx, v[i]); }
#pragma unroll
  for (int o = 32; o; o >>= 1) mx = fmaxf(mx, __shfl_xor(mx, o, 64));
  float se = 0.f;
#pragma unroll
  for (int i = 0; i < 8; i++) se += expf(v[i] - mx);
#pragma unroll
  for (int o = 32; o; o >>= 1) se += __shfl_xor(se, o, 64);
  __shared__ float r4[4];
  if (lane == 0) r4[w] = -(mx + logf(se));
  __syncthreads();
  if (t == 0) part[blockIdx.x] = r4[0] + r4[1] + r4[2] + r4[3];
}

// ---------------- Kernel E2: final mean ----------------
__global__ __launch_bounds__(256) void final_mean(
    const float* __restrict__ part, float* __restrict__ out) {
  int t = threadIdx.x, lane = t & 63, w = t >> 6;
  float acc = 0.f;
  for (int i = t; i < 2048; i += 256) acc += part[i];
#pragma unroll
  for (int o = 32; o; o >>= 1) acc += __shfl_down(acc, o, 64);
  __shared__ float r4[4];
  if (lane == 0) r4[w] = acc;
  __syncthreads();
  if (t == 0) out[0] = (r4[0] + r4[1] + r4[2] + r4[3]) * (1.0f / 8192.0f);
}

extern "C" void kernel_launch(void* const* d_in, const int* in_sizes, int n_in,
                              void* d_out, int out_size, void* d_ws, size_t ws_size,
                              hipStream_t stream) {
  const float* x         = (const float*)d_in[0];
  const float* mu        = (const float*)d_in[1];
  const float* dir_raw   = (const float*)d_in[2];
  const float* scale_rho = (const float*)d_in[3];
  const float* psi_rho   = (const float*)d_in[4];
  const float* pi_logits = (const float*)d_in[5];
  float* out = (float*)d_out;
  char* ws = (char*)d_ws;

  float* psi_inv          = (float*)(ws + OFF_PSI);
  float* logdetPsi        = (float*)(ws + OFF_LDP);
  float* logpi            = (float*)(ws + OFF_LOGPI);
  float* offk             = (float*)(ws + OFF_OFFK);
  float* Minv             = (float*)(ws + OFF_MINV);
  float* xPx              = (float*)(ws + OFF_XPX);
  unsigned char* xq       = (unsigned char*)(ws + OFF_XBF);
  unsigned char* Gq       = (unsigned char*)(ws + OFF_GT);
  float* ll               = (float*)(ws + OFF_LL);
  float* part             = (float*)(ws + OFF_PART);

  prep_psi<<<1, 256, 0, stream>>>(psi_rho, pi_logits, psi_inv, logdetPsi, logpi);
  prep_all<<<Kk + Bn, 256, 0, stream>>>(x, mu, dir_raw, scale_rho, psi_inv,
                                        offk, Minv, Gq, xq, xPx);
  dim3 g(Nn / BN, Bn / BM);  // (16, 32)
  gemm_ll<<<g, 512, 0, stream>>>(xq, Gq, Minv, offk, logpi, logdetPsi, xPx, ll);
  lse_rows<<<Bn / 4, 256, 0, stream>>>(ll, part);
  final_mean<<<1, 256, 0, stream>>>(part, out);
}